// Round 8
// baseline (318.317 us; speedup 1.0000x reference)
//
#include <hip/hip_runtime.h>

// PersonaGNN: 2-layer GAT, N=100000, E=600000 (+self loops), dims 128, fp32 io.
//
// R18 (this round): rebuild from the best MEASURED config (R14, 232.8us)
// applying only verified wins since:
//  - 256B-ALIGN all workspace buffers; HA/HB first. (R16/R17 regression: HA at
//    16B-aligned offset -> 256B row gathers straddle 3 lines, FETCH 87->121MB,
//    agg1 45->51us.)
//  - esrcp zeroing DELETED: u = (l<deg) ? slot : 0 cndmask (deg arrives with
//    the slot word; garbage never dereferenced). Memset now ~433KB.
//  - FRONT MERGE: scatter + Wf2-pack + gemm1 in ONE kernel (gemm blocks
//    self-pack W1 global->LDS; W1 is L2-hot). 3 dispatches -> 1.
//  - Tail reverted to R14's gat_agg_l2 (attn2/wsum algebra never beat it);
//    finalize fused via R17-verified last-block acq_rel handshake.
//  Net: 4 kernels + 1 memset (was 6 ops).
//
// R14: padded edge table + overflow list, 2 nodes/group agg. R12: branchless
// batched gathers. R11: m=eself softmax. R10: gemm2 fused into agg1.

#define NEG_SLOPE 0.2f

typedef __attribute__((ext_vector_type(8))) short bf16x8;
typedef __attribute__((ext_vector_type(4))) float f32x4;

__device__ __forceinline__ float leaky(float x) { return x > 0.0f ? x : NEG_SLOPE * x; }

__device__ __forceinline__ unsigned int bf16rne(float f) {
  unsigned int u = __float_as_uint(f);
  return (u + 0x7fffu + ((u >> 16) & 1u)) >> 16;
}
__device__ __forceinline__ unsigned int packbf(float a, float b) {
  return bf16rne(a) | (bf16rne(b) << 16);
}
__device__ __forceinline__ float bf_lo(unsigned int u) { return __uint_as_float(u << 16); }
__device__ __forceinline__ float bf_hi(unsigned int u) { return __uint_as_float(u & 0xffff0000u); }

__device__ __forceinline__ void accum8(float* a, float w, uint4 h) {
  a[0] += w * bf_lo(h.x); a[1] += w * bf_hi(h.x);
  a[2] += w * bf_lo(h.y); a[3] += w * bf_hi(h.y);
  a[4] += w * bf_lo(h.z); a[5] += w * bf_hi(h.z);
  a[6] += w * bf_lo(h.w); a[7] += w * bf_hi(h.w);
}

// ---- fused 2-node GAT aggregation (each 16-lane group owns nodes n0,n1) ----
// esrcp is NOT zeroed: padding lanes (l >= deg) select node 0 via cndmask.
__device__ __forceinline__ float2 gat_node2(
    const uint4* __restrict__ H4, const float* __restrict__ vas,
    const float* __restrict__ vad, const int* __restrict__ fill,
    const int* __restrict__ esrcp, const int2* __restrict__ ovf,
    const int* __restrict__ ovfn, int node0, int node1, int nclamp,
    int lane, int l, float* acc0, float* acc1) {
  // t=0 loads (addresses depend only on node ids)
  int t0 = esrcp[(size_t)node0 * 16 + l];
  int t1 = esrcp[(size_t)node1 * 16 + l];
  int dg0 = fill[node0];
  int dg1 = fill[node1];
  float ad0 = vad[node0], ad1 = vad[node1];
  float as0 = vas[node0], as1 = vas[node1];
  uint4 hs0 = H4[(size_t)node0 * 16 + l];
  uint4 hs1 = H4[(size_t)node1 * 16 + l];
  int u0 = (l < dg0) ? min(max(t0, 0), nclamp) : 0;
  int u1 = (l < dg1) ? min(max(t1, 0), nclamp) : 0;
  float vs0 = vas[u0];
  float vs1 = vas[u1];
  // batch-0 gathers for both nodes: 16 rows in flight
  uint4 hb0[8], hb1[8];
#pragma unroll
  for (int i = 0; i < 8; i++) {
    int ut = __shfl(u0, (lane & 48) + i, 64);
    hb0[i] = H4[(size_t)ut * 16 + l];
  }
#pragma unroll
  for (int i = 0; i < 8; i++) {
    int ut = __shfl(u1, (lane & 48) + i, 64);
    hb1[i] = H4[(size_t)ut * 16 + l];
  }
  const bool big0 = dg0 > 8, big1 = dg1 > 8;
  uint4 hc0[8];
  if (big0) {
#pragma unroll
    for (int i = 0; i < 8; i++) {
      int ut = __shfl(u0, (lane & 48) + 8 + i, 64);
      hc0[i] = H4[(size_t)ut * 16 + l];
    }
  }
  // weights (m = eself, shift-invariant; wself = 1)
  float es0 = leaky(as0 + ad0), es1 = leaky(as1 + ad1);
  float wj0 = (l < dg0) ? __expf(leaky(vs0 + ad0) - es0) : 0.f;
  float wj1 = (l < dg1) ? __expf(leaky(vs1 + ad1) - es1) : 0.f;
  float ds0 = wj0, ds1 = wj1;
#pragma unroll
  for (int o = 8; o; o >>= 1) ds0 += __shfl_xor(ds0, o, 16);
#pragma unroll
  for (int o = 8; o; o >>= 1) ds1 += __shfl_xor(ds1, o, 16);
  // accumulate node0 (frees hb0), then its batch-1
#pragma unroll
  for (int i = 0; i < 8; i++) {
    float w = __shfl(wj0, (lane & 48) + i, 64);
    accum8(acc0, w, hb0[i]);
  }
  if (big0) {
#pragma unroll
    for (int i = 0; i < 8; i++) {
      float w = __shfl(wj0, (lane & 48) + 8 + i, 64);
      accum8(acc0, w, hc0[i]);
    }
  }
  uint4 hc1[8];
  if (big1) {
#pragma unroll
    for (int i = 0; i < 8; i++) {
      int ut = __shfl(u1, (lane & 48) + 8 + i, 64);
      hc1[i] = H4[(size_t)ut * 16 + l];
    }
  }
#pragma unroll
  for (int i = 0; i < 8; i++) {
    float w = __shfl(wj1, (lane & 48) + i, 64);
    accum8(acc1, w, hb1[i]);
  }
  if (big1) {
#pragma unroll
    for (int i = 0; i < 8; i++) {
      float w = __shfl(wj1, (lane & 48) + 8 + i, 64);
      accum8(acc1, w, hc1[i]);
    }
  }
  // rare overflow fixups (deg > 16)
  if (dg0 > 16 || dg1 > 16) {
    int ovn = *ovfn;
    for (int k = 0; k < ovn; k++) {
      int2 ent = ovf[k];
      if (ent.x == node0) {
        float w = __expf(leaky(vas[ent.y] + ad0) - es0);
        ds0 += w;
        accum8(acc0, w, H4[(size_t)ent.y * 16 + l]);
      }
      if (ent.x == node1) {
        float w = __expf(leaky(vas[ent.y] + ad1) - es1);
        ds1 += w;
        accum8(acc1, w, H4[(size_t)ent.y * 16 + l]);
      }
    }
  }
  // self terms
  accum8(acc0, 1.0f, hs0);
  accum8(acc1, 1.0f, hs1);
  return make_float2(1.0f / (ds0 + 1.0f), 1.0f / (ds1 + 1.0f));
}

// ---------------- shared gemm tile pieces ----------------
__device__ __forceinline__ void cvt_f32(const float4* raw, bf16x8* xf) {
#pragma unroll
  for (int ks = 0; ks < 4; ks++) {
    union { bf16x8 v; unsigned int u[4]; } cv;
    cv.u[0] = packbf(raw[2 * ks].x, raw[2 * ks].y);
    cv.u[1] = packbf(raw[2 * ks].z, raw[2 * ks].w);
    cv.u[2] = packbf(raw[2 * ks + 1].x, raw[2 * ks + 1].y);
    cv.u[3] = packbf(raw[2 * ks + 1].z, raw[2 * ks + 1].w);
    xf[ks] = cv.v;
  }
}

__device__ __forceinline__ void mfma_tile(const unsigned short* WL, const bf16x8* xf,
                                          const float* __restrict__ a_s,
                                          const float* __restrict__ a_d,
                                          unsigned short* __restrict__ H,
                                          float* __restrict__ vas,
                                          float* __restrict__ vad, int myrow, bool act,
                                          int lane, int q) {
  f32x4 acc[8];
#pragma unroll
  for (int ct = 0; ct < 8; ct++) acc[ct] = (f32x4){0.f, 0.f, 0.f, 0.f};
#pragma unroll
  for (int ks = 0; ks < 4; ks++) {
    bf16x8 wf[8];
#pragma unroll
    for (int ct = 0; ct < 8; ct++)
      wf[ct] = *(const bf16x8*)&WL[(((ct << 2) + ks) << 9) + lane * 8];
#pragma unroll
    for (int ct = 0; ct < 8; ct++)
      acc[ct] = __builtin_amdgcn_mfma_f32_16x16x32_bf16(wf[ct], xf[ks], acc[ct], 0, 0, 0);
  }
  float ds = 0.f, dd = 0.f;
#pragma unroll
  for (int ct = 0; ct < 8; ct++) {
    const int c0 = ct * 16 + q * 4;
    float4 as4 = *(const float4*)&a_s[c0];
    float4 ad4 = *(const float4*)&a_d[c0];
    ds += acc[ct][0] * as4.x + acc[ct][1] * as4.y + acc[ct][2] * as4.z + acc[ct][3] * as4.w;
    dd += acc[ct][0] * ad4.x + acc[ct][1] * ad4.y + acc[ct][2] * ad4.z + acc[ct][3] * ad4.w;
    if (act) {
      uint2 o;
      o.x = packbf(acc[ct][0], acc[ct][1]);
      o.y = packbf(acc[ct][2], acc[ct][3]);
      *(uint2*)&H[(size_t)myrow * 128 + c0] = o;
    }
  }
  ds += __shfl_xor(ds, 16, 64);
  ds += __shfl_xor(ds, 32, 64);
  dd += __shfl_xor(dd, 16, 64);
  dd += __shfl_xor(dd, 32, 64);
  if (q == 0 && act) {
    vas[myrow] = ds;
    vad[myrow] = dd;
  }
}

// ------- FRONT: gemm1 (self-packed W1) + Wf2 pack + edge scatter, one kernel -------
// blocks [0,ngemm): gemm layer-1; block ngemm: pack Wf2; rest: scatter edges.
__global__ __launch_bounds__(256) void front_k(
    const float* __restrict__ Xf, const float* __restrict__ W1,
    const float* __restrict__ W2, unsigned short* __restrict__ Wf2,
    const int* __restrict__ src, const int* __restrict__ dst,
    int* __restrict__ fill, int* __restrict__ esrcp, int2* __restrict__ ovf,
    int* __restrict__ ovfn, const float* __restrict__ a_s,
    const float* __restrict__ a_d, unsigned short* __restrict__ H,
    float* __restrict__ vas, float* __restrict__ vad, int n, int nt16, int ngemm,
    int E) {
  const int b = blockIdx.x;
  if (b < ngemm) {
    __shared__ unsigned short WL[32 * 512];  // 32 KB
    const int lane = threadIdx.x & 63;
    const int wv = threadIdx.x >> 6;
    const int l15 = lane & 15;
    const int q = lane >> 4;
    const int t0 = b * 4 + wv;
    const int t1 = t0 + ngemm * 4;
    const int r0 = t0 * 16 + l15;
    const int r1 = t1 * 16 + l15;
    const bool wact0 = t0 < nt16;
    const bool wact1 = t1 < nt16;
    const bool act0 = wact0 && (r0 < n);
    const bool act1 = wact1 && (r1 < n);

    float4 raw0[8];
    if (wact0) {
#pragma unroll
      for (int ks = 0; ks < 4; ks++) {
        float4 z = {0.f, 0.f, 0.f, 0.f};
        raw0[2 * ks] = z;
        raw0[2 * ks + 1] = z;
        if (act0) {
          raw0[2 * ks] = *(const float4*)&Xf[(size_t)r0 * 128 + ks * 32 + q * 8];
          raw0[2 * ks + 1] = *(const float4*)&Xf[(size_t)r0 * 128 + ks * 32 + q * 8 + 4];
        }
      }
    }
    // self-pack W1 (fp32, L2-hot) into fragment-ordered LDS
    for (int idx = threadIdx.x; idx < 16384; idx += 256) {
      int j = idx & 7;
      int ln = (idx >> 3) & 63;
      int fid = idx >> 9;
      int ct = fid >> 2, ks = fid & 3;
      int qq = ln >> 4, ll = ln & 15;
      WL[idx] = (unsigned short)bf16rne(W1[(ks * 32 + qq * 8 + j) * 128 + ct * 16 + ll]);
    }
    __syncthreads();
    if (!wact0) return;

    float4 raw1[8];
    if (wact1) {
#pragma unroll
      for (int ks = 0; ks < 4; ks++) {
        float4 z = {0.f, 0.f, 0.f, 0.f};
        raw1[2 * ks] = z;
        raw1[2 * ks + 1] = z;
        if (act1) {
          raw1[2 * ks] = *(const float4*)&Xf[(size_t)r1 * 128 + ks * 32 + q * 8];
          raw1[2 * ks + 1] = *(const float4*)&Xf[(size_t)r1 * 128 + ks * 32 + q * 8 + 4];
        }
      }
    }

    bf16x8 xf[4];
    cvt_f32(raw0, xf);
    mfma_tile(WL, xf, a_s, a_d, H, vas, vad, r0, act0, lane, q);
    if (wact1) {
      cvt_f32(raw1, xf);
      mfma_tile(WL, xf, a_s, a_d, H, vas, vad, r1, act1, lane, q);
    }
    return;
  }
  if (b == ngemm) {  // pack Wf2 for agg1_gemm2
    for (int idx = threadIdx.x; idx < 16384; idx += 256) {
      int j = idx & 7;
      int ln = (idx >> 3) & 63;
      int fid = idx >> 9;
      int ct = fid >> 2, ks = fid & 3;
      int qq = ln >> 4, ll = ln & 15;
      Wf2[idx] = (unsigned short)bf16rne(W2[(ks * 32 + qq * 8 + j) * 128 + ct * 16 + ll]);
    }
    return;
  }
  // scatter edges into padded table + overflow list
  int e = (b - ngemm - 1) * 256 + threadIdx.x;
  if (e < E) {
    int v = dst[e];
    int sv = src[e];
    int p = atomicAdd(&fill[v], 1);
    if (p < 16) {
      esrcp[(size_t)v * 16 + p] = sv;
    } else {
      int k = atomicAdd(ovfn, 1);
      ovf[k] = make_int2(v, sv);
    }
  }
}

// ------------- FUSED agg layer-1 + gemm layer-2, 32 nodes/block -------------
__global__ __launch_bounds__(256, 3) void agg1_gemm2(
    const unsigned short* __restrict__ HA, const float* __restrict__ vas1,
    const float* __restrict__ vad1, const int* __restrict__ fill,
    const int* __restrict__ esrcp, const int2* __restrict__ ovf,
    const int* __restrict__ ovfn, const float* __restrict__ b1,
    const unsigned short* __restrict__ Wf2, const float* __restrict__ a_s2,
    const float* __restrict__ a_d2, unsigned short* __restrict__ HB,
    float* __restrict__ vas2, float* __restrict__ vad2, int n) {
  __shared__ unsigned short Atile[32 * 128];  // 8KB, 16B chunks XOR-swizzled by row&7
  __shared__ float sdot[2][2][4][16];         // [tile][s/d][wave][l]
  const int tid = threadIdx.x;
  const int lane = tid & 63;
  const int wv = tid >> 6;
  const int q = lane >> 4;
  const int l = lane & 15;
  const int row = wv * 4 + q;                  // 0..15
  const int base = blockIdx.x * 32;
  const int node0 = base + row;
  const int node1 = base + row + 16;
  const bool valid0 = node0 < n, valid1 = node1 < n;
  const int n0s = valid0 ? node0 : n - 1;
  const int n1s = valid1 ? node1 : n - 1;
  const uint4* __restrict__ H4 = (const uint4*)HA;

  float acc0[8], acc1[8];
#pragma unroll
  for (int k = 0; k < 8; k++) { acc0[k] = 0.f; acc1[k] = 0.f; }
  float2 inv = gat_node2(H4, vas1, vad1, fill, esrcp, ovf, ovfn, n0s, n1s, n - 1,
                         lane, l, acc0, acc1);

  float4 b0 = *(const float4*)&b1[8 * l];
  float4 b1v = *(const float4*)&b1[8 * l + 4];
  uint4 o0 = {0u, 0u, 0u, 0u}, o1 = {0u, 0u, 0u, 0u};
  if (valid0) {
    float r0_ = fmaxf(acc0[0] * inv.x + b0.x, 0.f), r1_ = fmaxf(acc0[1] * inv.x + b0.y, 0.f);
    float r2_ = fmaxf(acc0[2] * inv.x + b0.z, 0.f), r3_ = fmaxf(acc0[3] * inv.x + b0.w, 0.f);
    float r4_ = fmaxf(acc0[4] * inv.x + b1v.x, 0.f), r5_ = fmaxf(acc0[5] * inv.x + b1v.y, 0.f);
    float r6_ = fmaxf(acc0[6] * inv.x + b1v.z, 0.f), r7_ = fmaxf(acc0[7] * inv.x + b1v.w, 0.f);
    o0.x = packbf(r0_, r1_); o0.y = packbf(r2_, r3_);
    o0.z = packbf(r4_, r5_); o0.w = packbf(r6_, r7_);
  }
  if (valid1) {
    float r0_ = fmaxf(acc1[0] * inv.y + b0.x, 0.f), r1_ = fmaxf(acc1[1] * inv.y + b0.y, 0.f);
    float r2_ = fmaxf(acc1[2] * inv.y + b0.z, 0.f), r3_ = fmaxf(acc1[3] * inv.y + b0.w, 0.f);
    float r4_ = fmaxf(acc1[4] * inv.y + b1v.x, 0.f), r5_ = fmaxf(acc1[5] * inv.y + b1v.y, 0.f);
    float r6_ = fmaxf(acc1[6] * inv.y + b1v.z, 0.f), r7_ = fmaxf(acc1[7] * inv.y + b1v.w, 0.f);
    o1.x = packbf(r0_, r1_); o1.y = packbf(r2_, r3_);
    o1.z = packbf(r4_, r5_); o1.w = packbf(r6_, r7_);
  }
  *(uint4*)&Atile[row * 128 + ((l ^ (row & 7)) << 3)] = o0;
  *(uint4*)&Atile[(row + 16) * 128 + ((l ^ (row & 7)) << 3)] = o1;
  __syncthreads();

  // ---- gemm: two 16-row tiles, shared W frags from L2-hot Wf2 ----
  const int ct0 = 2 * wv, ct1 = 2 * wv + 1;
  f32x4 aA0 = {0.f, 0.f, 0.f, 0.f}, aB0 = aA0, aA1 = aA0, aB1 = aA0;
#pragma unroll
  for (int ks = 0; ks < 4; ks++) {
    bf16x8 w0 = *(const bf16x8*)&Wf2[(((ct0 << 2) + ks) << 9) + lane * 8];
    bf16x8 w1 = *(const bf16x8*)&Wf2[(((ct1 << 2) + ks) << 9) + lane * 8];
    bf16x8 x0 = *(const bf16x8*)&Atile[l * 128 + ((((ks << 2) + q) ^ (l & 7)) << 3)];
    bf16x8 x1 = *(const bf16x8*)&Atile[(16 + l) * 128 + ((((ks << 2) + q) ^ (l & 7)) << 3)];
    aA0 = __builtin_amdgcn_mfma_f32_16x16x32_bf16(w0, x0, aA0, 0, 0, 0);
    aB0 = __builtin_amdgcn_mfma_f32_16x16x32_bf16(w1, x0, aB0, 0, 0, 0);
    aA1 = __builtin_amdgcn_mfma_f32_16x16x32_bf16(w0, x1, aA1, 0, 0, 0);
    aB1 = __builtin_amdgcn_mfma_f32_16x16x32_bf16(w1, x1, aB1, 0, 0, 0);
  }

#pragma unroll
  for (int t = 0; t < 2; t++) {
    f32x4 aA = t ? aA1 : aA0;
    f32x4 aB = t ? aB1 : aB0;
    const int myrow = base + t * 16 + l;
    const bool ract = myrow < n;
    float ds = 0.f, dd = 0.f;
    {
      const int c0 = ct0 * 16 + q * 4;
      float4 as4 = *(const float4*)&a_s2[c0];
      float4 ad4 = *(const float4*)&a_d2[c0];
      ds += aA[0] * as4.x + aA[1] * as4.y + aA[2] * as4.z + aA[3] * as4.w;
      dd += aA[0] * ad4.x + aA[1] * ad4.y + aA[2] * ad4.z + aA[3] * ad4.w;
      if (ract) {
        uint2 ov;
        ov.x = packbf(aA[0], aA[1]);
        ov.y = packbf(aA[2], aA[3]);
        *(uint2*)&HB[(size_t)myrow * 128 + c0] = ov;
      }
    }
    {
      const int c0 = ct1 * 16 + q * 4;
      float4 as4 = *(const float4*)&a_s2[c0];
      float4 ad4 = *(const float4*)&a_d2[c0];
      ds += aB[0] * as4.x + aB[1] * as4.y + aB[2] * as4.z + aB[3] * as4.w;
      dd += aB[0] * ad4.x + aB[1] * ad4.y + aB[2] * ad4.z + aB[3] * ad4.w;
      if (ract) {
        uint2 ov;
        ov.x = packbf(aB[0], aB[1]);
        ov.y = packbf(aB[2], aB[3]);
        *(uint2*)&HB[(size_t)myrow * 128 + c0] = ov;
      }
    }
    ds += __shfl_xor(ds, 16, 64);
    ds += __shfl_xor(ds, 32, 64);
    dd += __shfl_xor(dd, 16, 64);
    dd += __shfl_xor(dd, 32, 64);
    if (q == 0) {
      sdot[t][0][wv][l] = ds;
      sdot[t][1][wv][l] = dd;
    }
  }
  __syncthreads();
  if (tid < 32) {
    int t = tid >> 4, i = tid & 15;
    int nn = base + tid;
    if (nn < n) {
      vas2[nn] = sdot[t][0][0][i] + sdot[t][0][1][i] + sdot[t][0][2][i] + sdot[t][0][3][i];
      vad2[nn] = sdot[t][1][0][i] + sdot[t][1][1][i] + sdot[t][1][2][i] + sdot[t][1][3][i];
    }
  }
}

// --- GAT agg layer-2 + mean partials + last-block finalize, 32 nodes/block ---
__global__ __launch_bounds__(256, 3) void gat_agg_l2(
    const unsigned short* __restrict__ H, const float* __restrict__ vas,
    const float* __restrict__ vad, const int* __restrict__ fill,
    const int* __restrict__ esrcp, const int2* __restrict__ ovf,
    const int* __restrict__ ovfn, const float* __restrict__ bias,
    float* __restrict__ partial, float* __restrict__ out, int* __restrict__ done,
    int n, float invn) {
  const int tid = threadIdx.x;
  const int lane = tid & 63;
  const int wv = tid >> 6;
  const int q = lane >> 4;
  const int l = lane & 15;
  const int row = wv * 4 + q;
  const int base = blockIdx.x * 32;
  const int node0 = base + row;
  const int node1 = base + row + 16;
  const bool valid0 = node0 < n, valid1 = node1 < n;
  const int n0s = valid0 ? node0 : n - 1;
  const int n1s = valid1 ? node1 : n - 1;
  const uint4* __restrict__ H4 = (const uint4*)H;

  float acc0[8], acc1[8];
#pragma unroll
  for (int k = 0; k < 8; k++) { acc0[k] = 0.f; acc1[k] = 0.f; }
  float2 inv = gat_node2(H4, vas, vad, fill, esrcp, ovf, ovfn, n0s, n1s, n - 1,
                         lane, l, acc0, acc1);

  float4 b0 = *(const float4*)&bias[8 * l];
  float4 b1v = *(const float4*)&bias[8 * l + 4];
  float o[8];
  const float i0 = valid0 ? inv.x : 0.f;
  const float i1 = valid1 ? inv.y : 0.f;
  const float bm = (valid0 ? 1.f : 0.f) + (valid1 ? 1.f : 0.f);
  o[0] = acc0[0] * i0 + acc1[0] * i1 + bm * b0.x;
  o[1] = acc0[1] * i0 + acc1[1] * i1 + bm * b0.y;
  o[2] = acc0[2] * i0 + acc1[2] * i1 + bm * b0.z;
  o[3] = acc0[3] * i0 + acc1[3] * i1 + bm * b0.w;
  o[4] = acc0[4] * i0 + acc1[4] * i1 + bm * b1v.x;
  o[5] = acc0[5] * i0 + acc1[5] * i1 + bm * b1v.y;
  o[6] = acc0[6] * i0 + acc1[6] * i1 + bm * b1v.z;
  o[7] = acc0[7] * i0 + acc1[7] * i1 + bm * b1v.w;

#pragma unroll
  for (int k = 0; k < 8; k++) {
    o[k] += __shfl_xor(o[k], 16, 64);
    o[k] += __shfl_xor(o[k], 32, 64);
  }
  __shared__ float red[4][128];
  if (q == 0) {
#pragma unroll
    for (int k = 0; k < 8; k++) red[wv][8 * l + k] = o[k];
  }
  __syncthreads();
  if (tid < 128) {
    float sm = red[0][tid] + red[1][tid] + red[2][tid] + red[3][tid];
    atomicAdd(&partial[(blockIdx.x & 63) * 128 + tid], sm);
  }
  __syncthreads();  // drains vmcnt -> this block's atomics complete

  // last-block finalize (R17-verified handshake: no threadfence)
  __shared__ int islast;
  if (tid == 0) {
    int v = __hip_atomic_fetch_add(done, 1, __ATOMIC_ACQ_REL, __HIP_MEMORY_SCOPE_AGENT);
    islast = (v == (int)gridDim.x - 1) ? 1 : 0;
  }
  __syncthreads();
  if (islast && tid < 128) {
    float s = 0.f;
#pragma unroll 8
    for (int r = 0; r < 64; r++)
      s += __hip_atomic_load(&partial[r * 128 + tid], __ATOMIC_RELAXED,
                             __HIP_MEMORY_SCOPE_AGENT);
    out[tid] = s * invn;
  }
}

extern "C" void kernel_launch(void* const* d_in, const int* in_sizes, int n_in,
                              void* d_out, int out_size, void* d_ws, size_t ws_size,
                              hipStream_t stream) {
  const float* x = (const float*)d_in[0];
  const int* ei = (const int*)d_in[1];
  const float* W1 = (const float*)d_in[2];
  const float* a_src1 = (const float*)d_in[3];
  const float* a_dst1 = (const float*)d_in[4];
  const float* b1 = (const float*)d_in[5];
  const float* W2 = (const float*)d_in[6];
  const float* a_src2 = (const float*)d_in[7];
  const float* a_dst2 = (const float*)d_in[8];
  const float* b2 = (const float*)d_in[9];
  float* out = (float*)d_out;

  const int N = in_sizes[0] / 128;
  const int E = in_sizes[1] / 2;
  const int* src = ei;
  const int* dst = ei + E;

  const size_t rowpadded = (size_t)(N + 256) * 128;

  // 256B-aligned workspace carve-out
  char* p = (char*)d_ws;
  auto carve = [&p](size_t bytes) {
    char* r = p;
    p += (bytes + 255) & ~(size_t)255;
    return r;
  };
  unsigned short* HA = (unsigned short*)carve(rowpadded * 2);  // 256-row-aligned
  unsigned short* HB = (unsigned short*)carve(rowpadded * 2);
  // contiguous zero region (one small memset): fill | partial | done | ovfn
  char* zstart = p;
  int* fill = (int*)carve((size_t)N * 4);
  float* partial = (float*)carve(64 * 128 * 4);
  int* done = (int*)carve(256);
  int* ovfn = (int*)carve(256);
  const size_t zsize = (size_t)(p - zstart);
  // non-zeroed
  float* vas1 = (float*)carve((size_t)N * 4);
  float* vad1 = (float*)carve((size_t)N * 4);
  float* vas2 = (float*)carve((size_t)N * 4);
  float* vad2 = (float*)carve((size_t)N * 4);
  int* esrcp = (int*)carve((size_t)N * 16 * 4);  // padded edge table, NOT zeroed
  int2* ovf = (int2*)carve((size_t)E * 8);
  unsigned short* Wf2 = (unsigned short*)carve(16384 * 2);

  const int eblocks = (E + 255) / 256;
  const int nt16 = (N + 15) / 16;
  const int ngemm = (nt16 + 7) / 8;     // 2 tiles per wave
  const int aggblocks = (N + 31) / 32;  // 32 nodes per 256-thread block

  // 1. zero fill/partial/done/ovfn (~433KB)
  hipMemsetAsync(zstart, 0, zsize, stream);
  // 2. front: gemm1 (self-packed W1) + Wf2 pack + edge scatter
  front_k<<<ngemm + 1 + eblocks, 256, 0, stream>>>(
      x, W1, W2, Wf2, src, dst, fill, esrcp, ovf, ovfn, a_src1, a_dst1, HA, vas1,
      vad1, N, nt16, ngemm, E);
  // 3. fused agg layer-1 + gemm layer-2
  agg1_gemm2<<<aggblocks, 256, 0, stream>>>(HA, vas1, vad1, fill, esrcp, ovf, ovfn, b1,
                                            Wf2, a_src2, a_dst2, HB, vas2, vad2, N);
  // 4. agg layer-2 + mean partials + fused finalize
  gat_agg_l2<<<aggblocks, 256, 0, stream>>>(HB, vas2, vad2, fill, esrcp, ovf, ovfn, b2,
                                            partial, out, done, N, 1.0f / (float)N);
}

// Round 9
// 238.893 us; speedup vs baseline: 1.3325x; 1.3325x over previous
//
#include <hip/hip_runtime.h>

// PersonaGNN: 2-layer GAT, N=100000, E=600000 (+self loops), dims 128, fp32 io.
//
// R19 (this round):
//  - HANDSHAKE FENCE REMOVED: R18's gat_agg_l2 3x regression (120us, VALUBusy
//    10% vs agg1's 35% with IDENTICAL gather code) was the ACQ_REL agent-scope
//    fetch_add: per-block L2 writeback/invalidate x 3125 blocks thrashed the
//    gather working set of all co-resident blocks (FETCH normal -> L3
//    absorbed; latency regime L2->L3). Fix: RELAXED fetch_add (no cache
//    maintenance). Correctness: partial's device-scope atomics complete at
//    the coherence point before __syncthreads' vmcnt(0) drain; done-RMW
//    serializes at the same L3 point; last block reads partial via
//    agent-scope atomic loads (R18 proved values correct).
//  - W-pack loops: coalesced float4 global loads + scattered LDS/global
//    stores (was 64 scattered global loads/thread).
//
// R18 (verified kept): 256B-aligned workspace (agg1 FETCH 121->88MB
// confirmed), esrcp not zeroed (dg-guard cndmask), front merge
// (gemm1+Wf2pack+scatter), 4 kernels + 1 memset.
// R14: padded edge table + overflow, 2 nodes/group agg. R12: branchless
// batched gathers. R11: m=eself softmax. R10: gemm2 fused into agg1.

#define NEG_SLOPE 0.2f

typedef __attribute__((ext_vector_type(8))) short bf16x8;
typedef __attribute__((ext_vector_type(4))) float f32x4;

__device__ __forceinline__ float leaky(float x) { return x > 0.0f ? x : NEG_SLOPE * x; }

__device__ __forceinline__ unsigned int bf16rne(float f) {
  unsigned int u = __float_as_uint(f);
  return (u + 0x7fffu + ((u >> 16) & 1u)) >> 16;
}
__device__ __forceinline__ unsigned int packbf(float a, float b) {
  return bf16rne(a) | (bf16rne(b) << 16);
}
__device__ __forceinline__ float bf_lo(unsigned int u) { return __uint_as_float(u << 16); }
__device__ __forceinline__ float bf_hi(unsigned int u) { return __uint_as_float(u & 0xffff0000u); }

__device__ __forceinline__ void accum8(float* a, float w, uint4 h) {
  a[0] += w * bf_lo(h.x); a[1] += w * bf_hi(h.x);
  a[2] += w * bf_lo(h.y); a[3] += w * bf_hi(h.y);
  a[4] += w * bf_lo(h.z); a[5] += w * bf_hi(h.z);
  a[6] += w * bf_lo(h.w); a[7] += w * bf_hi(h.w);
}

// coalesced W pack: thread loads float4 at linear e, stores 4 bf16 to packed idx.
// packed: Wf[((ct*4+ks)<<9) + lane*8 + j], r=ks*32+q*8+j (row), c=ct*16+l15,
// lane=q*16+l15. e = r*128+c.
__device__ __forceinline__ void pack_w(const float* __restrict__ W,
                                       unsigned short* __restrict__ Wf, int tid) {
#pragma unroll
  for (int pass = 0; pass < 16; pass++) {
    const int e = pass * 1024 + tid * 4;
    float4 v = *(const float4*)&W[e];
    const int r = e >> 7, c0 = e & 127;
    const int ks = r >> 5, q = (r >> 3) & 3, j = r & 7;
    const int ct = c0 >> 4, l15 = c0 & 15;
    const int base = (((ct << 2) + ks) << 9) + ((q << 4) + l15) * 8 + j;
    Wf[base] = (unsigned short)bf16rne(v.x);
    Wf[base + 8] = (unsigned short)bf16rne(v.y);
    Wf[base + 16] = (unsigned short)bf16rne(v.z);
    Wf[base + 24] = (unsigned short)bf16rne(v.w);
  }
}

// ---- fused 2-node GAT aggregation (each 16-lane group owns nodes n0,n1) ----
// esrcp is NOT zeroed: padding lanes (l >= deg) select node 0 via cndmask.
__device__ __forceinline__ float2 gat_node2(
    const uint4* __restrict__ H4, const float* __restrict__ vas,
    const float* __restrict__ vad, const int* __restrict__ fill,
    const int* __restrict__ esrcp, const int2* __restrict__ ovf,
    const int* __restrict__ ovfn, int node0, int node1, int nclamp,
    int lane, int l, float* acc0, float* acc1) {
  // t=0 loads (addresses depend only on node ids)
  int t0 = esrcp[(size_t)node0 * 16 + l];
  int t1 = esrcp[(size_t)node1 * 16 + l];
  int dg0 = fill[node0];
  int dg1 = fill[node1];
  float ad0 = vad[node0], ad1 = vad[node1];
  float as0 = vas[node0], as1 = vas[node1];
  uint4 hs0 = H4[(size_t)node0 * 16 + l];
  uint4 hs1 = H4[(size_t)node1 * 16 + l];
  int u0 = (l < dg0) ? min(max(t0, 0), nclamp) : 0;
  int u1 = (l < dg1) ? min(max(t1, 0), nclamp) : 0;
  float vs0 = vas[u0];
  float vs1 = vas[u1];
  // batch-0 gathers for both nodes: 16 rows in flight
  uint4 hb0[8], hb1[8];
#pragma unroll
  for (int i = 0; i < 8; i++) {
    int ut = __shfl(u0, (lane & 48) + i, 64);
    hb0[i] = H4[(size_t)ut * 16 + l];
  }
#pragma unroll
  for (int i = 0; i < 8; i++) {
    int ut = __shfl(u1, (lane & 48) + i, 64);
    hb1[i] = H4[(size_t)ut * 16 + l];
  }
  const bool big0 = dg0 > 8, big1 = dg1 > 8;
  uint4 hc0[8];
  if (big0) {
#pragma unroll
    for (int i = 0; i < 8; i++) {
      int ut = __shfl(u0, (lane & 48) + 8 + i, 64);
      hc0[i] = H4[(size_t)ut * 16 + l];
    }
  }
  // weights (m = eself, shift-invariant; wself = 1)
  float es0 = leaky(as0 + ad0), es1 = leaky(as1 + ad1);
  float wj0 = (l < dg0) ? __expf(leaky(vs0 + ad0) - es0) : 0.f;
  float wj1 = (l < dg1) ? __expf(leaky(vs1 + ad1) - es1) : 0.f;
  float ds0 = wj0, ds1 = wj1;
#pragma unroll
  for (int o = 8; o; o >>= 1) ds0 += __shfl_xor(ds0, o, 16);
#pragma unroll
  for (int o = 8; o; o >>= 1) ds1 += __shfl_xor(ds1, o, 16);
  // accumulate node0 (frees hb0), then its batch-1
#pragma unroll
  for (int i = 0; i < 8; i++) {
    float w = __shfl(wj0, (lane & 48) + i, 64);
    accum8(acc0, w, hb0[i]);
  }
  if (big0) {
#pragma unroll
    for (int i = 0; i < 8; i++) {
      float w = __shfl(wj0, (lane & 48) + 8 + i, 64);
      accum8(acc0, w, hc0[i]);
    }
  }
  uint4 hc1[8];
  if (big1) {
#pragma unroll
    for (int i = 0; i < 8; i++) {
      int ut = __shfl(u1, (lane & 48) + 8 + i, 64);
      hc1[i] = H4[(size_t)ut * 16 + l];
    }
  }
#pragma unroll
  for (int i = 0; i < 8; i++) {
    float w = __shfl(wj1, (lane & 48) + i, 64);
    accum8(acc1, w, hb1[i]);
  }
  if (big1) {
#pragma unroll
    for (int i = 0; i < 8; i++) {
      float w = __shfl(wj1, (lane & 48) + 8 + i, 64);
      accum8(acc1, w, hc1[i]);
    }
  }
  // rare overflow fixups (deg > 16)
  if (dg0 > 16 || dg1 > 16) {
    int ovn = *ovfn;
    for (int k = 0; k < ovn; k++) {
      int2 ent = ovf[k];
      if (ent.x == node0) {
        float w = __expf(leaky(vas[ent.y] + ad0) - es0);
        ds0 += w;
        accum8(acc0, w, H4[(size_t)ent.y * 16 + l]);
      }
      if (ent.x == node1) {
        float w = __expf(leaky(vas[ent.y] + ad1) - es1);
        ds1 += w;
        accum8(acc1, w, H4[(size_t)ent.y * 16 + l]);
      }
    }
  }
  // self terms
  accum8(acc0, 1.0f, hs0);
  accum8(acc1, 1.0f, hs1);
  return make_float2(1.0f / (ds0 + 1.0f), 1.0f / (ds1 + 1.0f));
}

// ---------------- shared gemm tile pieces ----------------
__device__ __forceinline__ void cvt_f32(const float4* raw, bf16x8* xf) {
#pragma unroll
  for (int ks = 0; ks < 4; ks++) {
    union { bf16x8 v; unsigned int u[4]; } cv;
    cv.u[0] = packbf(raw[2 * ks].x, raw[2 * ks].y);
    cv.u[1] = packbf(raw[2 * ks].z, raw[2 * ks].w);
    cv.u[2] = packbf(raw[2 * ks + 1].x, raw[2 * ks + 1].y);
    cv.u[3] = packbf(raw[2 * ks + 1].z, raw[2 * ks + 1].w);
    xf[ks] = cv.v;
  }
}

__device__ __forceinline__ void mfma_tile(const unsigned short* WL, const bf16x8* xf,
                                          const float* __restrict__ a_s,
                                          const float* __restrict__ a_d,
                                          unsigned short* __restrict__ H,
                                          float* __restrict__ vas,
                                          float* __restrict__ vad, int myrow, bool act,
                                          int lane, int q) {
  f32x4 acc[8];
#pragma unroll
  for (int ct = 0; ct < 8; ct++) acc[ct] = (f32x4){0.f, 0.f, 0.f, 0.f};
#pragma unroll
  for (int ks = 0; ks < 4; ks++) {
    bf16x8 wf[8];
#pragma unroll
    for (int ct = 0; ct < 8; ct++)
      wf[ct] = *(const bf16x8*)&WL[(((ct << 2) + ks) << 9) + lane * 8];
#pragma unroll
    for (int ct = 0; ct < 8; ct++)
      acc[ct] = __builtin_amdgcn_mfma_f32_16x16x32_bf16(wf[ct], xf[ks], acc[ct], 0, 0, 0);
  }
  float ds = 0.f, dd = 0.f;
#pragma unroll
  for (int ct = 0; ct < 8; ct++) {
    const int c0 = ct * 16 + q * 4;
    float4 as4 = *(const float4*)&a_s[c0];
    float4 ad4 = *(const float4*)&a_d[c0];
    ds += acc[ct][0] * as4.x + acc[ct][1] * as4.y + acc[ct][2] * as4.z + acc[ct][3] * as4.w;
    dd += acc[ct][0] * ad4.x + acc[ct][1] * ad4.y + acc[ct][2] * ad4.z + acc[ct][3] * ad4.w;
    if (act) {
      uint2 o;
      o.x = packbf(acc[ct][0], acc[ct][1]);
      o.y = packbf(acc[ct][2], acc[ct][3]);
      *(uint2*)&H[(size_t)myrow * 128 + c0] = o;
    }
  }
  ds += __shfl_xor(ds, 16, 64);
  ds += __shfl_xor(ds, 32, 64);
  dd += __shfl_xor(dd, 16, 64);
  dd += __shfl_xor(dd, 32, 64);
  if (q == 0 && act) {
    vas[myrow] = ds;
    vad[myrow] = dd;
  }
}

// ------- FRONT: gemm1 (self-packed W1) + Wf2 pack + edge scatter, one kernel -------
__global__ __launch_bounds__(256) void front_k(
    const float* __restrict__ Xf, const float* __restrict__ W1,
    const float* __restrict__ W2, unsigned short* __restrict__ Wf2,
    const int* __restrict__ src, const int* __restrict__ dst,
    int* __restrict__ fill, int* __restrict__ esrcp, int2* __restrict__ ovf,
    int* __restrict__ ovfn, const float* __restrict__ a_s,
    const float* __restrict__ a_d, unsigned short* __restrict__ H,
    float* __restrict__ vas, float* __restrict__ vad, int n, int nt16, int ngemm,
    int E) {
  const int b = blockIdx.x;
  if (b < ngemm) {
    __shared__ unsigned short WL[32 * 512];  // 32 KB
    const int lane = threadIdx.x & 63;
    const int wv = threadIdx.x >> 6;
    const int l15 = lane & 15;
    const int q = lane >> 4;
    const int t0 = b * 4 + wv;
    const int t1 = t0 + ngemm * 4;
    const int r0 = t0 * 16 + l15;
    const int r1 = t1 * 16 + l15;
    const bool wact0 = t0 < nt16;
    const bool wact1 = t1 < nt16;
    const bool act0 = wact0 && (r0 < n);
    const bool act1 = wact1 && (r1 < n);

    float4 raw0[8];
    if (wact0) {
#pragma unroll
      for (int ks = 0; ks < 4; ks++) {
        float4 z = {0.f, 0.f, 0.f, 0.f};
        raw0[2 * ks] = z;
        raw0[2 * ks + 1] = z;
        if (act0) {
          raw0[2 * ks] = *(const float4*)&Xf[(size_t)r0 * 128 + ks * 32 + q * 8];
          raw0[2 * ks + 1] = *(const float4*)&Xf[(size_t)r0 * 128 + ks * 32 + q * 8 + 4];
        }
      }
    }
    // self-pack W1 (coalesced float4 loads, L2-hot) into fragment-ordered LDS
    pack_w(W1, WL, threadIdx.x);
    __syncthreads();
    if (!wact0) return;

    float4 raw1[8];
    if (wact1) {
#pragma unroll
      for (int ks = 0; ks < 4; ks++) {
        float4 z = {0.f, 0.f, 0.f, 0.f};
        raw1[2 * ks] = z;
        raw1[2 * ks + 1] = z;
        if (act1) {
          raw1[2 * ks] = *(const float4*)&Xf[(size_t)r1 * 128 + ks * 32 + q * 8];
          raw1[2 * ks + 1] = *(const float4*)&Xf[(size_t)r1 * 128 + ks * 32 + q * 8 + 4];
        }
      }
    }

    bf16x8 xf[4];
    cvt_f32(raw0, xf);
    mfma_tile(WL, xf, a_s, a_d, H, vas, vad, r0, act0, lane, q);
    if (wact1) {
      cvt_f32(raw1, xf);
      mfma_tile(WL, xf, a_s, a_d, H, vas, vad, r1, act1, lane, q);
    }
    return;
  }
  if (b == ngemm) {  // pack Wf2 (global) for agg1_gemm2
    pack_w(W2, Wf2, threadIdx.x);
    return;
  }
  // scatter edges into padded table + overflow list
  int e = (b - ngemm - 1) * 256 + threadIdx.x;
  if (e < E) {
    int v = dst[e];
    int sv = src[e];
    int p = atomicAdd(&fill[v], 1);
    if (p < 16) {
      esrcp[(size_t)v * 16 + p] = sv;
    } else {
      int k = atomicAdd(ovfn, 1);
      ovf[k] = make_int2(v, sv);
    }
  }
}

// ------------- FUSED agg layer-1 + gemm layer-2, 32 nodes/block -------------
__global__ __launch_bounds__(256, 3) void agg1_gemm2(
    const unsigned short* __restrict__ HA, const float* __restrict__ vas1,
    const float* __restrict__ vad1, const int* __restrict__ fill,
    const int* __restrict__ esrcp, const int2* __restrict__ ovf,
    const int* __restrict__ ovfn, const float* __restrict__ b1,
    const unsigned short* __restrict__ Wf2, const float* __restrict__ a_s2,
    const float* __restrict__ a_d2, unsigned short* __restrict__ HB,
    float* __restrict__ vas2, float* __restrict__ vad2, int n) {
  __shared__ unsigned short Atile[32 * 128];  // 8KB, 16B chunks XOR-swizzled by row&7
  __shared__ float sdot[2][2][4][16];         // [tile][s/d][wave][l]
  const int tid = threadIdx.x;
  const int lane = tid & 63;
  const int wv = tid >> 6;
  const int q = lane >> 4;
  const int l = lane & 15;
  const int row = wv * 4 + q;                  // 0..15
  const int base = blockIdx.x * 32;
  const int node0 = base + row;
  const int node1 = base + row + 16;
  const bool valid0 = node0 < n, valid1 = node1 < n;
  const int n0s = valid0 ? node0 : n - 1;
  const int n1s = valid1 ? node1 : n - 1;
  const uint4* __restrict__ H4 = (const uint4*)HA;

  float acc0[8], acc1[8];
#pragma unroll
  for (int k = 0; k < 8; k++) { acc0[k] = 0.f; acc1[k] = 0.f; }
  float2 inv = gat_node2(H4, vas1, vad1, fill, esrcp, ovf, ovfn, n0s, n1s, n - 1,
                         lane, l, acc0, acc1);

  float4 b0 = *(const float4*)&b1[8 * l];
  float4 b1v = *(const float4*)&b1[8 * l + 4];
  uint4 o0 = {0u, 0u, 0u, 0u}, o1 = {0u, 0u, 0u, 0u};
  if (valid0) {
    float r0_ = fmaxf(acc0[0] * inv.x + b0.x, 0.f), r1_ = fmaxf(acc0[1] * inv.x + b0.y, 0.f);
    float r2_ = fmaxf(acc0[2] * inv.x + b0.z, 0.f), r3_ = fmaxf(acc0[3] * inv.x + b0.w, 0.f);
    float r4_ = fmaxf(acc0[4] * inv.x + b1v.x, 0.f), r5_ = fmaxf(acc0[5] * inv.x + b1v.y, 0.f);
    float r6_ = fmaxf(acc0[6] * inv.x + b1v.z, 0.f), r7_ = fmaxf(acc0[7] * inv.x + b1v.w, 0.f);
    o0.x = packbf(r0_, r1_); o0.y = packbf(r2_, r3_);
    o0.z = packbf(r4_, r5_); o0.w = packbf(r6_, r7_);
  }
  if (valid1) {
    float r0_ = fmaxf(acc1[0] * inv.y + b0.x, 0.f), r1_ = fmaxf(acc1[1] * inv.y + b0.y, 0.f);
    float r2_ = fmaxf(acc1[2] * inv.y + b0.z, 0.f), r3_ = fmaxf(acc1[3] * inv.y + b0.w, 0.f);
    float r4_ = fmaxf(acc1[4] * inv.y + b1v.x, 0.f), r5_ = fmaxf(acc1[5] * inv.y + b1v.y, 0.f);
    float r6_ = fmaxf(acc1[6] * inv.y + b1v.z, 0.f), r7_ = fmaxf(acc1[7] * inv.y + b1v.w, 0.f);
    o1.x = packbf(r0_, r1_); o1.y = packbf(r2_, r3_);
    o1.z = packbf(r4_, r5_); o1.w = packbf(r6_, r7_);
  }
  *(uint4*)&Atile[row * 128 + ((l ^ (row & 7)) << 3)] = o0;
  *(uint4*)&Atile[(row + 16) * 128 + ((l ^ (row & 7)) << 3)] = o1;
  __syncthreads();

  // ---- gemm: two 16-row tiles, shared W frags from L2-hot Wf2 ----
  const int ct0 = 2 * wv, ct1 = 2 * wv + 1;
  f32x4 aA0 = {0.f, 0.f, 0.f, 0.f}, aB0 = aA0, aA1 = aA0, aB1 = aA0;
#pragma unroll
  for (int ks = 0; ks < 4; ks++) {
    bf16x8 w0 = *(const bf16x8*)&Wf2[(((ct0 << 2) + ks) << 9) + lane * 8];
    bf16x8 w1 = *(const bf16x8*)&Wf2[(((ct1 << 2) + ks) << 9) + lane * 8];
    bf16x8 x0 = *(const bf16x8*)&Atile[l * 128 + ((((ks << 2) + q) ^ (l & 7)) << 3)];
    bf16x8 x1 = *(const bf16x8*)&Atile[(16 + l) * 128 + ((((ks << 2) + q) ^ (l & 7)) << 3)];
    aA0 = __builtin_amdgcn_mfma_f32_16x16x32_bf16(w0, x0, aA0, 0, 0, 0);
    aB0 = __builtin_amdgcn_mfma_f32_16x16x32_bf16(w1, x0, aB0, 0, 0, 0);
    aA1 = __builtin_amdgcn_mfma_f32_16x16x32_bf16(w0, x1, aA1, 0, 0, 0);
    aB1 = __builtin_amdgcn_mfma_f32_16x16x32_bf16(w1, x1, aB1, 0, 0, 0);
  }

#pragma unroll
  for (int t = 0; t < 2; t++) {
    f32x4 aA = t ? aA1 : aA0;
    f32x4 aB = t ? aB1 : aB0;
    const int myrow = base + t * 16 + l;
    const bool ract = myrow < n;
    float ds = 0.f, dd = 0.f;
    {
      const int c0 = ct0 * 16 + q * 4;
      float4 as4 = *(const float4*)&a_s2[c0];
      float4 ad4 = *(const float4*)&a_d2[c0];
      ds += aA[0] * as4.x + aA[1] * as4.y + aA[2] * as4.z + aA[3] * as4.w;
      dd += aA[0] * ad4.x + aA[1] * ad4.y + aA[2] * ad4.z + aA[3] * ad4.w;
      if (ract) {
        uint2 ov;
        ov.x = packbf(aA[0], aA[1]);
        ov.y = packbf(aA[2], aA[3]);
        *(uint2*)&HB[(size_t)myrow * 128 + c0] = ov;
      }
    }
    {
      const int c0 = ct1 * 16 + q * 4;
      float4 as4 = *(const float4*)&a_s2[c0];
      float4 ad4 = *(const float4*)&a_d2[c0];
      ds += aB[0] * as4.x + aB[1] * as4.y + aB[2] * as4.z + aB[3] * as4.w;
      dd += aB[0] * ad4.x + aB[1] * ad4.y + aB[2] * ad4.z + aB[3] * ad4.w;
      if (ract) {
        uint2 ov;
        ov.x = packbf(aB[0], aB[1]);
        ov.y = packbf(aB[2], aB[3]);
        *(uint2*)&HB[(size_t)myrow * 128 + c0] = ov;
      }
    }
    ds += __shfl_xor(ds, 16, 64);
    ds += __shfl_xor(ds, 32, 64);
    dd += __shfl_xor(dd, 16, 64);
    dd += __shfl_xor(dd, 32, 64);
    if (q == 0) {
      sdot[t][0][wv][l] = ds;
      sdot[t][1][wv][l] = dd;
    }
  }
  __syncthreads();
  if (tid < 32) {
    int t = tid >> 4, i = tid & 15;
    int nn = base + tid;
    if (nn < n) {
      vas2[nn] = sdot[t][0][0][i] + sdot[t][0][1][i] + sdot[t][0][2][i] + sdot[t][0][3][i];
      vad2[nn] = sdot[t][1][0][i] + sdot[t][1][1][i] + sdot[t][1][2][i] + sdot[t][1][3][i];
    }
  }
}

// --- GAT agg layer-2 + mean partials + last-block finalize, 32 nodes/block ---
__global__ __launch_bounds__(256, 3) void gat_agg_l2(
    const unsigned short* __restrict__ H, const float* __restrict__ vas,
    const float* __restrict__ vad, const int* __restrict__ fill,
    const int* __restrict__ esrcp, const int2* __restrict__ ovf,
    const int* __restrict__ ovfn, const float* __restrict__ bias,
    float* __restrict__ partial, float* __restrict__ out, int* __restrict__ done,
    int n, float invn) {
  const int tid = threadIdx.x;
  const int lane = tid & 63;
  const int wv = tid >> 6;
  const int q = lane >> 4;
  const int l = lane & 15;
  const int row = wv * 4 + q;
  const int base = blockIdx.x * 32;
  const int node0 = base + row;
  const int node1 = base + row + 16;
  const bool valid0 = node0 < n, valid1 = node1 < n;
  const int n0s = valid0 ? node0 : n - 1;
  const int n1s = valid1 ? node1 : n - 1;
  const uint4* __restrict__ H4 = (const uint4*)H;

  float acc0[8], acc1[8];
#pragma unroll
  for (int k = 0; k < 8; k++) { acc0[k] = 0.f; acc1[k] = 0.f; }
  float2 inv = gat_node2(H4, vas, vad, fill, esrcp, ovf, ovfn, n0s, n1s, n - 1,
                         lane, l, acc0, acc1);

  float4 b0 = *(const float4*)&bias[8 * l];
  float4 b1v = *(const float4*)&bias[8 * l + 4];
  float o[8];
  const float i0 = valid0 ? inv.x : 0.f;
  const float i1 = valid1 ? inv.y : 0.f;
  const float bm = (valid0 ? 1.f : 0.f) + (valid1 ? 1.f : 0.f);
  o[0] = acc0[0] * i0 + acc1[0] * i1 + bm * b0.x;
  o[1] = acc0[1] * i0 + acc1[1] * i1 + bm * b0.y;
  o[2] = acc0[2] * i0 + acc1[2] * i1 + bm * b0.z;
  o[3] = acc0[3] * i0 + acc1[3] * i1 + bm * b0.w;
  o[4] = acc0[4] * i0 + acc1[4] * i1 + bm * b1v.x;
  o[5] = acc0[5] * i0 + acc1[5] * i1 + bm * b1v.y;
  o[6] = acc0[6] * i0 + acc1[6] * i1 + bm * b1v.z;
  o[7] = acc0[7] * i0 + acc1[7] * i1 + bm * b1v.w;

#pragma unroll
  for (int k = 0; k < 8; k++) {
    o[k] += __shfl_xor(o[k], 16, 64);
    o[k] += __shfl_xor(o[k], 32, 64);
  }
  __shared__ float red[4][128];
  if (q == 0) {
#pragma unroll
    for (int k = 0; k < 8; k++) red[wv][8 * l + k] = o[k];
  }
  __syncthreads();
  if (tid < 128) {
    float sm = red[0][tid] + red[1][tid] + red[2][tid] + red[3][tid];
    atomicAdd(&partial[(blockIdx.x & 63) * 128 + tid], sm);
  }
  __syncthreads();  // drains vmcnt -> this block's atomics complete at L3

  // last-block finalize: RELAXED handshake (NO cache maintenance; R18's
  // ACQ_REL emitted per-block L2 inv/wb -> 3x kernel slowdown).
  __shared__ int islast;
  if (tid == 0) {
    int v = __hip_atomic_fetch_add(done, 1, __ATOMIC_RELAXED, __HIP_MEMORY_SCOPE_AGENT);
    islast = (v == (int)gridDim.x - 1) ? 1 : 0;
  }
  __syncthreads();
  if (islast && tid < 128) {
    float s = 0.f;
#pragma unroll 8
    for (int r = 0; r < 64; r++)
      s += __hip_atomic_load(&partial[r * 128 + tid], __ATOMIC_RELAXED,
                             __HIP_MEMORY_SCOPE_AGENT);
    out[tid] = s * invn;
  }
}

extern "C" void kernel_launch(void* const* d_in, const int* in_sizes, int n_in,
                              void* d_out, int out_size, void* d_ws, size_t ws_size,
                              hipStream_t stream) {
  const float* x = (const float*)d_in[0];
  const int* ei = (const int*)d_in[1];
  const float* W1 = (const float*)d_in[2];
  const float* a_src1 = (const float*)d_in[3];
  const float* a_dst1 = (const float*)d_in[4];
  const float* b1 = (const float*)d_in[5];
  const float* W2 = (const float*)d_in[6];
  const float* a_src2 = (const float*)d_in[7];
  const float* a_dst2 = (const float*)d_in[8];
  const float* b2 = (const float*)d_in[9];
  float* out = (float*)d_out;

  const int N = in_sizes[0] / 128;
  const int E = in_sizes[1] / 2;
  const int* src = ei;
  const int* dst = ei + E;

  const size_t rowpadded = (size_t)(N + 256) * 128;

  // 256B-aligned workspace carve-out
  char* p = (char*)d_ws;
  auto carve = [&p](size_t bytes) {
    char* r = p;
    p += (bytes + 255) & ~(size_t)255;
    return r;
  };
  unsigned short* HA = (unsigned short*)carve(rowpadded * 2);  // 256-row-aligned
  unsigned short* HB = (unsigned short*)carve(rowpadded * 2);
  // contiguous zero region (one small memset): fill | partial | done | ovfn
  char* zstart = p;
  int* fill = (int*)carve((size_t)N * 4);
  float* partial = (float*)carve(64 * 128 * 4);
  int* done = (int*)carve(256);
  int* ovfn = (int*)carve(256);
  const size_t zsize = (size_t)(p - zstart);
  // non-zeroed
  float* vas1 = (float*)carve((size_t)N * 4);
  float* vad1 = (float*)carve((size_t)N * 4);
  float* vas2 = (float*)carve((size_t)N * 4);
  float* vad2 = (float*)carve((size_t)N * 4);
  int* esrcp = (int*)carve((size_t)N * 16 * 4);  // padded edge table, NOT zeroed
  int2* ovf = (int2*)carve((size_t)E * 8);
  unsigned short* Wf2 = (unsigned short*)carve(16384 * 2);

  const int eblocks = (E + 255) / 256;
  const int nt16 = (N + 15) / 16;
  const int ngemm = (nt16 + 7) / 8;     // 2 tiles per wave
  const int aggblocks = (N + 31) / 32;  // 32 nodes per 256-thread block

  // 1. zero fill/partial/done/ovfn (~433KB)
  hipMemsetAsync(zstart, 0, zsize, stream);
  // 2. front: gemm1 (self-packed W1) + Wf2 pack + edge scatter
  front_k<<<ngemm + 1 + eblocks, 256, 0, stream>>>(
      x, W1, W2, Wf2, src, dst, fill, esrcp, ovf, ovfn, a_src1, a_dst1, HA, vas1,
      vad1, N, nt16, ngemm, E);
  // 3. fused agg layer-1 + gemm layer-2
  agg1_gemm2<<<aggblocks, 256, 0, stream>>>(HA, vas1, vad1, fill, esrcp, ovf, ovfn, b1,
                                            Wf2, a_src2, a_dst2, HB, vas2, vad2, N);
  // 4. agg layer-2 + mean partials + fused finalize (relaxed handshake)
  gat_agg_l2<<<aggblocks, 256, 0, stream>>>(HB, vas2, vad2, fill, esrcp, ovf, ovfn, b2,
                                            partial, out, done, N, 1.0f / (float)N);
}